// Round 1
// baseline (230.378 us; speedup 1.0000x reference)
//
#include <hip/hip_runtime.h>
#include <math.h>

// SafetyConstraint: per-row CBF value.
// lie = g_pos·vel + g_quat·quat_dot + g_vel·vel_dot  (all other grad entries are 0)
// cbf = clip(clip(lie,-100,100) + 2*h, -20, 20)

__global__ __launch_bounds__(256) void SafetyConstraint_68238440398980_kernel(
    const float* __restrict__ state,
    const float* __restrict__ action,
    float* __restrict__ out,
    int nrows)
{
    int row = blockIdx.x * 256 + threadIdx.x;
    if (row >= nrows) return;

    const float* s = state + (long long)row * 18;

    // row base byte offset = 72*row -> always 8B aligned: float2 loads are safe
    float2 f0 = *reinterpret_cast<const float2*>(s + 0);   // px, py
    float2 f1 = *reinterpret_cast<const float2*>(s + 2);   // pz, q0
    float2 f2 = *reinterpret_cast<const float2*>(s + 4);   // q1, q2
    float2 f3 = *reinterpret_cast<const float2*>(s + 6);   // q3, vx
    float2 f4 = *reinterpret_cast<const float2*>(s + 8);   // vy, vz
    float2 f5 = *reinterpret_cast<const float2*>(s + 10);  // wx, wy
    float wz = s[12];
    float a0 = action[(long long)row * 4];

    float px = f0.x, py = f0.y, pz = f1.x;
    float q0 = f1.y, q1 = f2.x, q2 = f2.y, q3 = f3.x;
    float vx = f3.y, vy = f4.x, vz = f4.y;
    float wx = f5.x, wy = f5.y;

    const float EPS = 1e-8f;
    const float BETA = 5.0f;

    // normalized quaternion
    float nsq = q0*q0 + q1*q1 + q2*q2 + q3*q3;
    float n = sqrtf(nsq);
    float inv = 1.0f / (n + EPS);
    float qw = q0*inv, qx = q1*inv, qy = q2*inv, qz = q3*inv;

    // barriers
    float b0 = pz - 0.4f;
    float b1 = 1.6f - pz;
    float b2 = 1.0f - px*px;
    float b3 = 1.0f - py*py;
    float b4 = 0.16f - (vx*vx + vy*vy + vz*vz);
    float aqw = fabsf(qw);
    float qwc = fminf(fmaxf(aqw, 0.1f), 1.0f);
    float b5 = qwc - 0.75f;

    // softmin h = -logsumexp(-beta*b)/beta ; weights = softmax(-beta*b)
    float x0 = -BETA*b0, x1 = -BETA*b1, x2 = -BETA*b2,
          x3 = -BETA*b3, x4 = -BETA*b4, x5 = -BETA*b5;
    float m = fmaxf(fmaxf(fmaxf(x0, x1), fmaxf(x2, x3)), fmaxf(x4, x5));
    float e0 = __expf(x0 - m), e1 = __expf(x1 - m), e2 = __expf(x2 - m),
          e3 = __expf(x3 - m), e4 = __expf(x4 - m), e5 = __expf(x5 - m);
    float se = e0 + e1 + e2 + e3 + e4 + e5;
    float inv_se = 1.0f / se;
    float h = -(m + __logf(se)) / BETA;

    float w0 = e0*inv_se, w1 = e1*inv_se, w2 = e2*inv_se,
          w3 = e3*inv_se, w4 = e4*inv_se, w5 = e5*inv_se;

    // --- term 1: grad wrt pos · sdot[0:3]=vel
    float gpx = -2.0f*px*w2;
    float gpy = -2.0f*py*w3;
    float gpz = w0 - w1;
    float term1 = gpx*vx + gpy*vy + gpz*vz;

    // --- term 2: grad wrt quat_raw · quat_dot
    float qd0 = 0.5f*(-qx*wx - qy*wy - qz*wz);
    float qd1 = 0.5f*( qw*wx + qy*wz - qz*wy);
    float qd2 = 0.5f*( qw*wy + qz*wx - qx*wz);
    float qd3 = 0.5f*( qw*wz + qx*wy - qy*wx);
    // c5: d b5 / d qw (normalized) -- clip(|qw|,0.1,1): qw<1 strictly always
    float c5 = (aqw > 0.1f) ? ((q0 >= 0.0f) ? w5 : -w5) : 0.0f;
    // gq_j = c5 * ( delta_{0j}*inv - q0*q_j*inv^2/n )
    // q_raw . qd = (n+eps)*(qhat . qd)  (analytically ~0, keep for fidelity)
    float dot_nqd = qw*qd0 + qx*qd1 + qy*qd2 + qz*qd3;   // qhat . qd
    float invn = 1.0f / n;
    float term2 = c5 * (qd0*inv - q0*dot_nqd*inv*invn);

    // --- term 3: grad wrt vel · vel_dot = gvz * az
    float gvz = -2.0f*vz*w4;
    float thrust = fminf(fmaxf(a0, 0.0f), 0.35f);
    float R33 = fminf(fmaxf(1.0f - 2.0f*(qx*qx + qy*qy), -1.0f), 1.0f);
    float az = thrust * R33 * (1.0f / 0.027f) - 9.81f;
    float term3 = gvz * az;

    float lie = term1 + term2 + term3;
    float h_dot = fminf(fmaxf(lie, -100.0f), 100.0f);
    float cbf = fminf(fmaxf(h_dot + 2.0f*h, -20.0f), 20.0f);

    out[row] = cbf;
}

extern "C" void kernel_launch(void* const* d_in, const int* in_sizes, int n_in,
                              void* d_out, int out_size, void* d_ws, size_t ws_size,
                              hipStream_t stream) {
    const float* state  = (const float*)d_in[0];
    const float* action = (const float*)d_in[1];
    float* out = (float*)d_out;
    int nrows = in_sizes[0] / 18;
    int grid = (nrows + 255) / 256;
    SafetyConstraint_68238440398980_kernel<<<grid, 256, 0, stream>>>(state, action, out, nrows);
}